// Round 6
// baseline (642.699 us; speedup 1.0000x reference)
//
#include <hip/hip_runtime.h>

#define D0 64
#define D1 1024
#define D2 1024
#define KST 5
#define W   32                 // d2 strip width incl. 2*KST halo
#define TT  22                 // valid strip width
#define NSTRIP 47
#define NSEG 16
#define SEGLEN 64
#define NWG (NSTRIP * NSEG)    // 752
#define COEFF 0.05f
#define CHALF 0.025f
#define PS2 (D0 * W / 2)       // u32 (bf16x2) per LDS plane = 1024
#define ROWSTR ((size_t)D1 * (size_t)D2)

typedef float4 f4;
typedef unsigned int u32;
typedef unsigned short u16;

struct PG { static constexpr bool steady = false; static constexpr int par = 0; };
struct P0 { static constexpr bool steady = true;  static constexpr int par = 0; };
struct P1 { static constexpr bool steady = true;  static constexpr int par = 1; };

__device__ __forceinline__ f4 ld4(const float* p) { return *(const f4*)p; }
__device__ __forceinline__ void st4(float* p, f4 v) { *(f4*)p = v; }
__device__ __forceinline__ int clampi(int v, int lo, int hi) {
    v = v < lo ? lo : v; return v > hi ? hi : v;
}

// ---- bf16 pack/unpack. pk via v_perm_b32: dst = hi16(b):hi16(a) ----
__device__ __forceinline__ u32 pk(float a, float b) {
    return __builtin_amdgcn_perm(__float_as_uint(b), __float_as_uint(a), 0x07060302u);
}
__device__ __forceinline__ uint2 pk4(f4 v) { return make_uint2(pk(v.x, v.y), pk(v.z, v.w)); }
__device__ __forceinline__ f4 upk4(uint2 w) {
    return make_float4(__uint_as_float(w.x << 16), __uint_as_float(w.x & 0xFFFF0000u),
                       __uint_as_float(w.y << 16), __uint_as_float(w.y & 0xFFFF0000u));
}
__device__ __forceinline__ f4 ldb(const u32* p) { return upk4(*(const uint2*)p); }
__device__ __forceinline__ void stb(u32* p, f4 v) { *(uint2*)p = pk4(v); }
__device__ __forceinline__ float bf2f(u16 h) { return __uint_as_float((u32)h << 16); }
__device__ __forceinline__ u16 f2bf(float f) {      // RTNE
    u32 u = __float_as_uint(f);
    u += 0x7FFFu + ((u >> 16) & 1u);
    return (u16)(u >> 16);
}

// XCD swizzle, NWG=752 divisible by 8: contiguous 94-tile chunk per XCD.
__device__ __forceinline__ int swz(int orig) { return (orig & 7) * (NWG / 8) + (orig >> 3); }

// Bank-spread involution (swaps storage of rows 2k/2k+1 when row&2): makes
// 2-row-strided um/dn reads conflict-free (<=2-way). Applied on ALL accesses.
__device__ __forceinline__ int swoff(int row, int cu) {
    return (row * (W / 2) + cu) ^ ((row & 2) << 3);
}

// lane i <- lane i-1 (row_shr:1). Cross-group lanes have c4==0 garbage col.
__device__ __forceinline__ float dpp_shr1(float x) {
    return __int_as_float(__builtin_amdgcn_update_dpp(0, __float_as_int(x), 0x111, 0xf, 0xf, true));
}
// lane i <- lane i+1 (row_shl:1). Cross-group lanes have c4==28 garbage col.
__device__ __forceinline__ float dpp_shl1(float x) {
    return __int_as_float(__builtin_amdgcn_update_dpp(0, __float_as_int(x), 0x101, 0xf, 0xf, true));
}

template<bool FIX2>
__device__ __forceinline__ f4 sten(f4 c, f4 zm, f4 zp, f4 um, f4 dn,
                                   float csr, f4 cx, float czf, int xlo, int xhi) {
    f4 xm = make_float4(dpp_shr1(c.w), c.x, c.y, c.z);
    f4 xp = make_float4(c.y, c.z, c.w, dpp_shl1(c.x));
    if (FIX2) {
        if (xlo == 0) xm.x = c.x;
        if (xlo == 1) xm.y = c.y;
        if (xlo == 2) xm.z = c.z;
        if (xlo == 3) xm.w = c.w;
        if (xhi == 0) xp.x = c.x;
        if (xhi == 1) xp.y = c.y;
        if (xhi == 2) xp.z = c.z;
        if (xhi == 3) xp.w = c.w;
    }
    f4 o;
    o.x = c.x + cx.x * (xp.x - xm.x) + csr * (dn.x - um.x) + czf * (zp.x - zm.x);
    o.y = c.y + cx.y * (xp.y - xm.y) + csr * (dn.y - um.y) + czf * (zp.y - zm.y);
    o.z = c.z + cx.z * (xp.z - xm.z) + csr * (dn.z - um.z) + czf * (zp.z - zm.z);
    o.w = c.w + cx.w * (xp.w - xm.w) + csr * (dn.w - um.w) + czf * (zp.w - zm.w);
    return o;
}

// PASS 0: f32 src -> bf16 ws.  PASS 1: bf16 ws -> f32 dst.
// 2-row threads: thread owns d0-rows r0=2g (A) and r1=2g+1 (B). Row A's dn and
// row B's um are the thread's own lag registers; only rows r0-1 / r1+1 come
// from LDS -> LDS reads per point halved vs 1-row mapping.
template<int PASS, bool FIX2>
__device__ __forceinline__ void run(const void* __restrict__ srcv, void* __restrict__ dstv,
                                    u32* lds, int g, int c4, int h2, int a, int bE) {
    const float* srcf = (const float*)srcv;
    const u16*   srch = (const u16*)srcv;
    u16*   dsth = (u16*)dstv;
    float* dstf = (float*)dstv;

    const int r0 = 2 * g, r1 = 2 * g + 1;
    const int cu = c4 >> 1;
    const int off_c0 = swoff(r0, cu);
    const int off_c1 = swoff(r1, cu);
    const int off_um = swoff(r0 == 0 ? 0 : r0 - 1, cu);        // clamped (edge reads own row)
    const int off_dn = swoff(r1 == D0 - 1 ? D0 - 1 : r1 + 1, cu);
    const float csr0 = (r0 == 0) ? COEFF : CHALF;
    const float csr1 = (r1 == D0 - 1) ? COEFF : CHALF;

    f4 cx;
    {
        const int gb = h2 + c4;
        cx.x = (gb + 0 == 0 || gb + 0 == D2 - 1) ? COEFF : CHALF;
        cx.y = (gb + 1 == 0 || gb + 1 == D2 - 1) ? COEFF : CHALF;
        cx.z = (gb + 2 == 0 || gb + 2 == D2 - 1) ? COEFF : CHALF;
        cx.w = (gb + 3 == 0 || gb + 3 == D2 - 1) ? COEFF : CHALF;
    }
    int xlo = -1, xhi = -1;
    if (FIX2) {
        const int aa = -(h2 + c4);
        const int bb = (D2 - 1) - (h2 + c4);
        if (aa >= 0 && aa < 4) xlo = aa;
        if (bb >= 0 && bb < 4) xhi = bb;
    }

    int gc0, gc1, gc2, gc3;
    if (FIX2) {
        gc0 = clampi(h2 + c4 + 0, 0, D2 - 1);
        gc1 = clampi(h2 + c4 + 1, 0, D2 - 1);
        gc2 = clampi(h2 + c4 + 2, 0, D2 - 1);
        gc3 = clampi(h2 + c4 + 3, 0, D2 - 1);
    } else {
        gc0 = h2 + c4; gc1 = gc0 + 1; gc2 = gc0 + 2; gc3 = gc0 + 3;
    }
    auto gloadA = [&](int p) -> f4 {
        if (PASS == 0) {
            const float* pp = srcf + (size_t)r0 * ROWSTR + (size_t)p * D2;
            if (FIX2) return make_float4(pp[gc0], pp[gc1], pp[gc2], pp[gc3]);
            return ld4(pp + gc0);
        } else {
            const u16* pp = srch + (size_t)r0 * ROWSTR + (size_t)p * D2;
            return make_float4(bf2f(pp[gc0]), bf2f(pp[gc1]), bf2f(pp[gc2]), bf2f(pp[gc3]));
        }
    };
    auto gloadB = [&](int p) -> f4 {
        if (PASS == 0) {
            const float* pp = srcf + (size_t)r1 * ROWSTR + (size_t)p * D2;
            if (FIX2) return make_float4(pp[gc0], pp[gc1], pp[gc2], pp[gc3]);
            return ld4(pp + gc0);
        } else {
            const u16* pp = srch + (size_t)r1 * ROWSTR + (size_t)p * D2;
            return make_float4(bf2f(pp[gc0]), bf2f(pp[gc1]), bf2f(pp[gc2]), bf2f(pp[gc3]));
        }
    };

    u16*   dbhA = dsth + (size_t)r0 * ROWSTR + h2;
    u16*   dbhB = dsth + (size_t)r1 * ROWSTR + h2;
    float* dbfA = dstf + (size_t)r0 * ROWSTR + h2;
    float* dbfB = dstf + (size_t)r1 * ROWSTR + h2;

    const int t0   = max(a - KST, 0);
    const int hiIn = min(bE + KST, D1);
    const int lo1 = max(a - 4, 0), hi1 = min(bE + 4, D1);
    const int lo2 = max(a - 3, 0), hi2 = min(bE + 3, D1);
    const int lo3 = max(a - 2, 0), hi3 = min(bE + 2, D1);
    const int lo4 = max(a - 1, 0), hi4 = min(bE + 1, D1);
    const int lo5 = a,             hi5 = bE;

    // register state (per row: input lags l0,l1,nxt + 4 stage lag pairs)
    f4 Al0, Al1, Anxt, Bl0, Bl1, Bnxt;
    f4 As1l0, As1l1, As2l0, As2l1, As3l0, As3l1, As4l0, As4l1;
    f4 Bs1l0, Bs1l1, Bs2l0, Bs2l1, Bs3l0, Bs3l1, Bs4l0, Bs4l1;

    Anxt = gloadA(t0);  Bnxt = gloadB(t0);
    Al0 = Al1 = Anxt;   Bl0 = Bl1 = Bnxt;
    As1l0 = As1l1 = As2l0 = As2l1 = As3l0 = As3l1 = As4l0 = As4l1 = Anxt;
    Bs1l0 = Bs1l1 = Bs2l0 = Bs2l1 = Bs3l0 = Bs3l1 = Bs4l0 = Bs4l1 = Bnxt;

    auto body = [&](int t, auto TAG) __attribute__((always_inline)) {
        constexpr bool ST = decltype(TAG)::steady;
        constexpr int PAR = decltype(TAG)::par;

        // distance-1 prefetch (plane t+1)
        f4 tA = gloadA(min(t + 1, D1 - 1));
        f4 tB = gloadB(min(t + 1, D1 - 1));

        f4 Anv1 = As1l0, Anv2 = As2l0, Anv3 = As3l0, Anv4 = As4l0;
        f4 Bnv1 = Bs1l0, Bnv2 = Bs2l0, Bnv3 = Bs3l0, Bnv4 = Bs4l0;

        // ---- stage 1: input regs + ring0 um/dn -> ring1 ----
        if (ST || (t - 1 >= lo1 && t - 1 < hi1)) {
            const int p = t - 1;
            const int sl = ST ? (PAR ^ 1) : (p & 1);
            const u32* pl = lds + sl * PS2;
            f4 um = ldb(pl + off_um);
            f4 dn = ldb(pl + off_dn);
            f4 cA = Al0, cB = Bl0;
            f4 zmA = (!ST && p == 0)      ? cA : Al1;
            f4 zpA = (!ST && p == D1 - 1) ? cA : Anxt;
            f4 zmB = (!ST && p == 0)      ? cB : Bl1;
            f4 zpB = (!ST && p == D1 - 1) ? cB : Bnxt;
            const float czf = (!ST && (p == 0 || p == D1 - 1)) ? COEFF : CHALF;
            Anv1 = sten<FIX2>(cA, zmA, zpA, um, cB, csr0, cx, czf, xlo, xhi);
            Bnv1 = sten<FIX2>(cB, zmB, zpB, cA, dn, csr1, cx, czf, xlo, xhi);
            u32* wl = lds + (2 + sl) * PS2;
            stb(wl + off_c0, Anv1);
            stb(wl + off_c1, Bnv1);
        }

#define SG(S, AL0v, AL1v, ANVp, ANV, BL0v, BL1v, BNVp, BNV)                       \
        if (ST || (t - (S) >= lo##S && t - (S) < hi##S)) {                        \
            const int p = t - (S);                                                \
            const int sl = ST ? (PAR ^ ((S) & 1)) : (p & 1);                      \
            const u32* pl = lds + (2 * ((S) - 1) + sl) * PS2;                     \
            f4 um = ldb(pl + off_um);                                             \
            f4 dn = ldb(pl + off_dn);                                             \
            f4 cA = AL0v, cB = BL0v;                                              \
            f4 zmA = (!ST && p == 0)      ? cA : AL1v;                            \
            f4 zpA = (!ST && p == D1 - 1) ? cA : ANVp;                            \
            f4 zmB = (!ST && p == 0)      ? cB : BL1v;                            \
            f4 zpB = (!ST && p == D1 - 1) ? cB : BNVp;                            \
            const float czf = (!ST && (p == 0 || p == D1 - 1)) ? COEFF : CHALF;   \
            ANV = sten<FIX2>(cA, zmA, zpA, um, cB, csr0, cx, czf, xlo, xhi);      \
            BNV = sten<FIX2>(cB, zmB, zpB, cA, dn, csr1, cx, czf, xlo, xhi);      \
            u32* wl = lds + (2 * (S) + sl) * PS2;                                 \
            stb(wl + off_c0, ANV);                                                \
            stb(wl + off_c1, BNV);                                                \
        }
        SG(2, As1l0, As1l1, Anv1, Anv2, Bs1l0, Bs1l1, Bnv1, Bnv2)
        SG(3, As2l0, As2l1, Anv2, Anv3, Bs2l0, Bs2l1, Bnv2, Bnv3)
        SG(4, As3l0, As3l1, Anv3, Anv4, Bs3l0, Bs3l1, Bnv3, Bnv4)
#undef SG

        // ---- stage 5: ring4 um/dn + s4 lags -> global ----
        if (ST || (t - 5 >= lo5 && t - 5 < hi5)) {
            const int p = t - 5;
            const int sl = ST ? (PAR ^ 1) : (p & 1);
            const u32* pl = lds + (8 + sl) * PS2;
            f4 um = ldb(pl + off_um);
            f4 dn = ldb(pl + off_dn);
            f4 cA = As4l0, cB = Bs4l0;
            f4 zmA = (!ST && p == 0)      ? cA : As4l1;
            f4 zpA = (!ST && p == D1 - 1) ? cA : Anv4;
            f4 zmB = (!ST && p == 0)      ? cB : Bs4l1;
            f4 zpB = (!ST && p == D1 - 1) ? cB : Bnv4;
            const float czf = (!ST && (p == 0 || p == D1 - 1)) ? COEFF : CHALF;
            f4 oA = sten<FIX2>(cA, zmA, zpA, um, cB, csr0, cx, czf, xlo, xhi);
            f4 oB = sten<FIX2>(cB, zmB, zpB, cA, dn, csr1, cx, czf, xlo, xhi);
            if (PASS == 0) {
                u16* dA = dbhA + (size_t)p * D2;
                u16* dB = dbhB + (size_t)p * D2;
                if (c4 + 0 >= 5 && c4 + 0 <= 26) { dA[c4 + 0] = f2bf(oA.x); dB[c4 + 0] = f2bf(oB.x); }
                if (c4 + 1 >= 5 && c4 + 1 <= 26) { dA[c4 + 1] = f2bf(oA.y); dB[c4 + 1] = f2bf(oB.y); }
                if (c4 + 2 >= 5 && c4 + 2 <= 26) { dA[c4 + 2] = f2bf(oA.z); dB[c4 + 2] = f2bf(oB.z); }
                if (c4 + 3 >= 5 && c4 + 3 <= 26) { dA[c4 + 3] = f2bf(oA.w); dB[c4 + 3] = f2bf(oB.w); }
            } else {
                float* dA = dbfA + (size_t)p * D2;
                float* dB = dbfB + (size_t)p * D2;
                if (c4 >= 8 && c4 <= 20) {
                    st4(dA + c4, oA);
                    st4(dB + c4, oB);
                } else if (c4 == 4) {
                    dA[5] = oA.y; *(float2*)(dA + 6) = make_float2(oA.z, oA.w);
                    dB[5] = oB.y; *(float2*)(dB + 6) = make_float2(oB.z, oB.w);
                } else if (c4 == 24) {
                    *(float2*)(dA + 24) = make_float2(oA.x, oA.y); dA[26] = oA.z;
                    *(float2*)(dB + 24) = make_float2(oB.x, oB.y); dB[26] = oB.z;
                }
            }
        }

        // ---- commit input plane t ----
        if (ST || t < hiIn) {
            u32* wl = lds + (ST ? PAR : (t & 1)) * PS2;
            stb(wl + off_c0, Anxt);
            stb(wl + off_c1, Bnxt);
        }

        // ---- roll lags ----
        Al1 = Al0; Al0 = Anxt; Anxt = tA;
        Bl1 = Bl0; Bl0 = Bnxt; Bnxt = tB;
        As1l1 = As1l0; As1l0 = Anv1;  Bs1l1 = Bs1l0; Bs1l0 = Bnv1;
        As2l1 = As2l0; As2l0 = Anv2;  Bs2l1 = Bs2l0; Bs2l0 = Bnv2;
        As3l1 = As3l0; As3l0 = Anv3;  Bs3l1 = Bs3l0; Bs3l0 = Bnv3;
        As4l1 = As4l0; As4l0 = Anv4;  Bs4l1 = Bs4l0; Bs4l0 = Bnv4;
        __syncthreads();
    };

    int tSlo = t0 + 11; tSlo += (tSlo & 1);
    const int tEnd = bE + 4;
    const int tShi = min(bE + 4, D1 - 1);
    int t = t0;
    const int tP = min(tSlo, tEnd + 1);
#pragma unroll 1
    for (; t < tP; ++t) body(t, PG{});
#pragma unroll 1
    for (; t + 1 <= tShi; t += 2) { body(t, P0{}); body(t + 1, P1{}); }
#pragma unroll 1
    for (; t <= tEnd; ++t) body(t, PG{});
}

template<int PASS>
__global__ __launch_bounds__(256, 3) void diffusion_fused(const void* __restrict__ src,
                                                          void* __restrict__ dst) {
    __shared__ __align__(16) u32 lds[10 * PS2];   // 40960 B

    const int b = swz(blockIdx.x);
    const int seg = b / NSTRIP;
    const int strip = b - seg * NSTRIP;
    const int o2 = min(strip * TT, D2 - TT);
    const int h2 = o2 - KST;
    const int a  = seg * SEGLEN;
    const int bE = min(a + SEGLEN, D1);

    const int g  = threadIdx.x >> 3;          // 0..31 (rows 2g, 2g+1)
    const int c4 = (threadIdx.x & 7) << 2;    // 0..28

    if (o2 == 0 || o2 == D2 - TT) run<PASS, true >(src, dst, &lds[0], g, c4, h2, a, bE);
    else                          run<PASS, false>(src, dst, &lds[0], g, c4, h2, a, bE);
}

extern "C" void kernel_launch(void* const* d_in, const int* in_sizes, int n_in,
                              void* d_out, int out_size, void* d_ws, size_t ws_size,
                              hipStream_t stream) {
    const void* x  = d_in[0];
    void* out = d_out;
    void* ws  = d_ws;

    const dim3 grid(NWG);
    const dim3 block(256);

    diffusion_fused<0><<<grid, block, 0, stream>>>(x, ws);    // f32 -> bf16 ws
    diffusion_fused<1><<<grid, block, 0, stream>>>(ws, out);  // bf16 ws -> f32
}